// Round 5
// baseline (326.595 us; speedup 1.0000x reference)
//
#include <hip/hip_runtime.h>

#define C_ 512
#define T_ 2048
#define N_TOK 16384
#define K_CB 4096

typedef __attribute__((ext_vector_type(4))) float f32x4;
typedef __attribute__((ext_vector_type(8))) short short8;

static __device__ __forceinline__ unsigned short f2bf(float f) {
    unsigned u = __float_as_uint(f);
    unsigned r = (u + 0x7FFFu + ((u >> 16) & 1u)) >> 16;  // RNE
    return (unsigned short)r;
}

// ---------------- Kernel 1: transpose student (B,C,T)->(N,C) bf16 + per-token partial stats ------
__global__ __launch_bounds__(256) void k1_prep(
    const float* __restrict__ student,   // (B,C,T) fp32
    const int* __restrict__ codes,       // (B,T) int32
    const float* __restrict__ codebook,  // (K,C) fp32
    unsigned short* __restrict__ Abf,    // (N,C) bf16 out
    float* __restrict__ xnorm, float* __restrict__ dtg2)
{
    __shared__ float tile[64][65];
    __shared__ int lcodes[64];
    int tid = threadIdx.x;
    int tnum  = blockIdx.x >> 1;
    int chalf = blockIdx.x & 1;
    int b  = tnum >> 5;
    int t0 = (tnum & 31) << 6;
    int cbase = chalf << 8;             // 0 or 256
    int cx = tid & 63;                  // lane
    int q  = tid >> 6;                  // wave
    if (tid < 64) lcodes[tid] = codes[b * T_ + t0 + tid];
    __syncthreads();
    float ax2[16], ad2[16];
#pragma unroll
    for (int p = 0; p < 16; ++p) { ax2[p] = 0.f; ad2[p] = 0.f; }
    for (int c0 = cbase; c0 < cbase + 256; c0 += 64) {
#pragma unroll
        for (int p = 0; p < 16; ++p) {
            int ch = p * 4 + q;
            tile[ch][cx] = student[(size_t)b * (C_ * T_) + (size_t)(c0 + ch) * T_ + t0 + cx];
        }
        __syncthreads();
#pragma unroll
        for (int p = 0; p < 16; ++p) {
            int ty = p * 4 + q;
            float x = tile[cx][ty];
            int n = b * T_ + t0 + ty;
            Abf[(size_t)n * C_ + c0 + cx] = f2bf(x);
            ax2[p] += x * x;
            float cb = codebook[(size_t)lcodes[ty] * C_ + c0 + cx];
            float d = x - cb;
            ad2[p] += d * d;
        }
        __syncthreads();
    }
#pragma unroll
    for (int p = 0; p < 16; ++p) {
        float sx = ax2[p], sd = ad2[p];
#pragma unroll
        for (int m = 1; m < 64; m <<= 1) {
            sx += __shfl_xor(sx, m);
            sd += __shfl_xor(sd, m);
        }
        if (cx == 0) {
            int n = b * T_ + t0 + p * 4 + q;
            atomicAdd(&xnorm[n], sx);
            atomicAdd(&dtg2[n], sd);
        }
    }
}

// ---------------- Kernel 1b: codebook -> bf16 + row norms + init of all reduce buffers -----------
__global__ __launch_bounds__(256) void k1_cb(
    const float* __restrict__ codebook,
    unsigned short* __restrict__ CBbf,
    float* __restrict__ cbnorm,
    float* __restrict__ s_sum,
    unsigned long long* __restrict__ minpack,
    float* __restrict__ xnorm, float* __restrict__ dtg2,
    float* __restrict__ accum)
{
    int tid = threadIdx.x;
    int gidx = blockIdx.x * 256 + tid;
    if (gidx < N_TOK) {
        s_sum[gidx] = 0.f; minpack[gidx] = ~0ull;
        xnorm[gidx] = 0.f; dtg2[gidx] = 0.f;
    }
    if (gidx < 8) accum[gidx] = 0.f;
    int lane = tid & 63;
    int w = tid >> 6;
    int row = blockIdx.x * 4 + w;
    const float* src = codebook + (size_t)row * C_ + lane * 8;
    float4 v0 = *(const float4*)(src);
    float4 v1 = *(const float4*)(src + 4);
    float s = v0.x*v0.x + v0.y*v0.y + v0.z*v0.z + v0.w*v0.w
            + v1.x*v1.x + v1.y*v1.y + v1.z*v1.z + v1.w*v1.w;
    uint4 pk;
    pk.x = (unsigned)f2bf(v0.x) | ((unsigned)f2bf(v0.y) << 16);
    pk.y = (unsigned)f2bf(v0.z) | ((unsigned)f2bf(v0.w) << 16);
    pk.z = (unsigned)f2bf(v1.x) | ((unsigned)f2bf(v1.y) << 16);
    pk.w = (unsigned)f2bf(v1.z) | ((unsigned)f2bf(v1.w) << 16);
    *(uint4*)(CBbf + (size_t)row * C_ + lane * 8) = pk;
#pragma unroll
    for (int m = 1; m < 64; m <<= 1) s += __shfl_xor(s, m);
    if (lane == 0) cbnorm[row] = s;
}

// ---------------- Kernel 2: NO-LDS direct-fragment MFMA GEMM + distance epilogue ----------------
// Both A (N,C) and B=codebook (K,C) are K-major -> MFMA fragments are contiguous 16B vectors:
// one global_load_dwordx4 per fragment = 16 rows x 64 contiguous bytes (fully coalesced,
// L1/L2-served). No LDS, no barriers, no staging in the main loop. Waves free-run;
// 2 waves/SIMD hide load latency under MFMA.
// grid = 1024 (64 rb x 16 cb, XCD-swizzled); block = 512 (8 waves = 2x4, wave owns 128x64)
__global__ __launch_bounds__(512, 2) void k2_main(
    const unsigned short* __restrict__ Abf,
    const unsigned short* __restrict__ CBbf,
    const float* __restrict__ xnorm,
    const float* __restrict__ dtg2,
    const float* __restrict__ cbnorm,
    float* __restrict__ s_sum,
    unsigned long long* __restrict__ minpack)
{
    __shared__ float red_s[256 * 4];                    // 4 KB
    __shared__ unsigned long long red_m[256 * 4];       // 8 KB
    int tid = threadIdx.x;
    int lane = tid & 63;
    int w = tid >> 6;                   // 0..7
    int wr = w >> 2, wc = w & 3;        // 2 x 4 wave grid
    int l15 = lane & 15, hi = lane >> 4;

    // XCD-aware swizzle: 1024 % 8 == 0 -> contiguous 128-WG chunk per XCD
    // (keeps each XCD's A panels + all of B hot in its private L2)
    int orig = blockIdx.x;
    int swz = (orig & 7) * 128 + (orig >> 3);
    int rb = swz >> 4, cb = swz & 15;
    int row0 = rb * 256, col0 = cb * 256;

    // Per-lane fragment base pointers: lane l15 -> row, hi -> 16B k-chunk.
    const unsigned short* pA = Abf  + (size_t)(row0 + wr * 128 + l15) * C_ + hi * 8;
    const unsigned short* pB = CBbf + (size_t)(col0 + wc * 64  + l15) * C_ + hi * 8;

    f32x4 acc[8][4];
#pragma unroll
    for (int rt = 0; rt < 8; ++rt)
#pragma unroll
        for (int ct = 0; ct < 4; ++ct)
            acc[rt][ct] = (f32x4){0.f, 0.f, 0.f, 0.f};

#pragma unroll
    for (int t = 0; t < 16; ++t) {      // K = 512 = 16 x BK32; t*32 elems = +64B imm offset
        short8 af[8], bfr[4];
#pragma unroll
        for (int rt = 0; rt < 8; ++rt)
            af[rt] = *(const short8*)(pA + (size_t)rt * (16 * C_) + t * 32);
#pragma unroll
        for (int ct = 0; ct < 4; ++ct)
            bfr[ct] = *(const short8*)(pB + (size_t)ct * (16 * C_) + t * 32);
#pragma unroll
        for (int rt = 0; rt < 8; ++rt)
#pragma unroll
            for (int ct = 0; ct < 4; ++ct)
                acc[rt][ct] = __builtin_amdgcn_mfma_f32_16x16x32_bf16(af[rt], bfr[ct], acc[rt][ct], 0, 0, 0);
    }

    // ---------------- epilogue: dot -> distance -> exp-sum + argmin ----------------
    float cbn[4];
#pragma unroll
    for (int ct = 0; ct < 4; ++ct)
        cbn[ct] = cbnorm[col0 + wc * 64 + ct * 16 + l15];
#pragma unroll
    for (int rt = 0; rt < 8; ++rt) {
#pragma unroll
        for (int r = 0; r < 4; ++r) {
            int lrow = wr * 128 + rt * 16 + hi * 4 + r;  // 0..255 within tile
            int row = row0 + lrow;
            float xn = xnorm[row];
            float dt = sqrtf(dtg2[row]);
            float sv = 0.f, dm = 3.4e38f;
            unsigned ix = 0u;
#pragma unroll
            for (int ct = 0; ct < 4; ++ct) {
                float dot = acc[rt][ct][r];
                float d2 = fmaxf(xn + cbn[ct] - 2.f * dot, 0.f);
                float d = sqrtf(d2);
                sv += __expf(fminf(dt - d, 80.f));
                unsigned col = (unsigned)(col0 + wc * 64 + ct * 16 + l15);
                if (d < dm) { dm = d; ix = col; }
            }
#pragma unroll
            for (int m = 1; m < 16; m <<= 1) {
                sv += __shfl_xor(sv, m);
                float od = __shfl_xor(dm, m);
                unsigned oi = __shfl_xor(ix, m);
                if (od < dm || (od == dm && oi < ix)) { dm = od; ix = oi; }
            }
            if (l15 == 0) {
                red_s[lrow * 4 + wc] = sv;
                red_m[lrow * 4 + wc] = ((unsigned long long)__float_as_uint(dm) << 32)
                                     | (unsigned long long)ix;
            }
        }
    }
    __syncthreads();
    if (tid < 256) {
        float sv = red_s[tid * 4 + 0] + red_s[tid * 4 + 1]
                 + red_s[tid * 4 + 2] + red_s[tid * 4 + 3];
        unsigned long long pk = red_m[tid * 4 + 0];
        unsigned long long p1 = red_m[tid * 4 + 1]; if (p1 < pk) pk = p1;
        unsigned long long p2 = red_m[tid * 4 + 2]; if (p2 < pk) pk = p2;
        unsigned long long p3 = red_m[tid * 4 + 3]; if (p3 < pk) pk = p3;
        atomicAdd(&s_sum[row0 + tid], sv);
        atomicMin(&minpack[row0 + tid], pk);
    }
}

// ---------------- Kernel 3a: per-token CE/accuracy/emb-loss/target-dist reduce ----------------
__global__ __launch_bounds__(256) void k3a(
    const float* __restrict__ s_sum,
    const unsigned long long* __restrict__ minpack,
    const int* __restrict__ codes,
    const float* __restrict__ dtg2,
    float* __restrict__ accum)
{
    __shared__ float w0[4], w1[4], w2[4], w3[4];
    int tid = threadIdx.x;
    int n = blockIdx.x * 256 + tid;
    // s_sum[n] = sum_j exp(d_t - d_j)  =>  log(s_sum) = d_t + lse(-d) = per-token CE
    float ce = logf(s_sum[n]);
    unsigned pred = (unsigned)(minpack[n] & 0xFFFFFFFFull);
    float ok = (pred == (unsigned)codes[n]) ? 1.f : 0.f;
    float sq = dtg2[n];
    float td = sqrtf(sq);
#pragma unroll
    for (int m = 1; m < 64; m <<= 1) {
        ce += __shfl_xor(ce, m);
        ok += __shfl_xor(ok, m);
        sq += __shfl_xor(sq, m);
        td += __shfl_xor(td, m);
    }
    int lane = tid & 63, w = tid >> 6;
    if (lane == 0) { w0[w] = ce; w1[w] = ok; w2[w] = sq; w3[w] = td; }
    __syncthreads();
    if (tid == 0) {
        atomicAdd(&accum[0], w0[0] + w0[1] + w0[2] + w0[3]);
        atomicAdd(&accum[1], w1[0] + w1[1] + w1[2] + w1[3]);
        atomicAdd(&accum[2], w2[0] + w2[1] + w2[2] + w2[3]);
        atomicAdd(&accum[3], w3[0] + w3[1] + w3[2] + w3[3]);
    }
}

// ---------------- Kernel 3b: finalize 5 outputs ----------------
__global__ void k3b(const float* __restrict__ accum, float* __restrict__ out)
{
    if (threadIdx.x == 0 && blockIdx.x == 0) {
        float ce   = accum[0] / (float)N_TOK;
        float accy = accum[1] / (float)N_TOK;
        float emb  = accum[2] / ((float)N_TOK * (float)C_);
        float td   = accum[3] / (float)N_TOK;
        out[0] = emb + ce;   // total_loss (EMB_W=CE_W=1)
        out[1] = emb;        // emb_to_codebook_loss
        out[2] = ce;         // ce_loss
        out[3] = accy;       // token_accuracy
        out[4] = td;         // emb_to_target_dist
    }
}

extern "C" void kernel_launch(void* const* d_in, const int* in_sizes, int n_in,
                              void* d_out, int out_size, void* d_ws, size_t ws_size,
                              hipStream_t stream)
{
    const float* student  = (const float*)d_in[0];
    const int*   codes    = (const int*)d_in[1];
    const float* codebook = (const float*)d_in[2];
    // d_in[3] distance_matrix is unused by the reference.
    float* out = (float*)d_out;

    char* ws = (char*)d_ws;
    unsigned short* Abf   = (unsigned short*)(ws);                 // 16 MiB
    unsigned short* CBbf  = (unsigned short*)(ws + 16777216);      // 4 MiB
    float* xnorm          = (float*)(ws + 20971520);               // 64 KiB
    float* dtg2           = (float*)(ws + 21037056);               // 64 KiB
    float* cbnorm         = (float*)(ws + 21102592);               // 16 KiB
    float* s_sum          = (float*)(ws + 21118976);               // 64 KiB
    unsigned long long* minpack = (unsigned long long*)(ws + 21184512); // 128 KiB
    float* accum          = (float*)(ws + 21315584);               // 64 B

    // k1_cb zero-inits s_sum/minpack/xnorm/dtg2/accum (stream-ordered before k1_prep's atomics)
    hipLaunchKernelGGL(k1_cb, dim3(1024), dim3(256), 0, stream,
                       codebook, CBbf, cbnorm, s_sum, minpack, xnorm, dtg2, accum);
    hipLaunchKernelGGL(k1_prep, dim3(512), dim3(256), 0, stream,
                       student, codes, codebook, Abf, xnorm, dtg2);
    hipLaunchKernelGGL(k2_main, dim3(1024), dim3(512), 0, stream,
                       Abf, CBbf, xnorm, dtg2, cbnorm, s_sum, minpack);
    hipLaunchKernelGGL(k3a, dim3(64), dim3(256), 0, stream,
                       s_sum, minpack, codes, dtg2, accum);
    hipLaunchKernelGGL(k3b, dim3(1), dim3(64), 0, stream, accum, out);
}

// Round 6
// 217.805 us; speedup vs baseline: 1.4995x; 1.4995x over previous
//
#include <hip/hip_runtime.h>

#define C_ 512
#define T_ 2048
#define N_TOK 16384
#define K_CB 4096

typedef __attribute__((ext_vector_type(4))) float f32x4;
typedef __attribute__((ext_vector_type(8))) short short8;

static __device__ __forceinline__ unsigned short f2bf(float f) {
    unsigned u = __float_as_uint(f);
    unsigned r = (u + 0x7FFFu + ((u >> 16) & 1u)) >> 16;  // RNE
    return (unsigned short)r;
}

typedef const __attribute__((address_space(1))) void* gas_t;
typedef __attribute__((address_space(3))) void* las_t;
static __device__ __forceinline__ void stage16(const void* g, void* l) {
    __builtin_amdgcn_global_load_lds((gas_t)g, (las_t)l, 16, 0, 0);
}

// ---------------- Kernel 1: transpose student (B,C,T)->(N,C) bf16 + per-token partial stats ------
__global__ __launch_bounds__(256) void k1_prep(
    const float* __restrict__ student,   // (B,C,T) fp32
    const int* __restrict__ codes,       // (B,T) int32
    const float* __restrict__ codebook,  // (K,C) fp32
    unsigned short* __restrict__ Abf,    // (N,C) bf16 out
    float* __restrict__ xnorm, float* __restrict__ dtg2)
{
    __shared__ float tile[64][65];
    __shared__ int lcodes[64];
    int tid = threadIdx.x;
    int tnum  = blockIdx.x >> 1;
    int chalf = blockIdx.x & 1;
    int b  = tnum >> 5;
    int t0 = (tnum & 31) << 6;
    int cbase = chalf << 8;             // 0 or 256
    int cx = tid & 63;                  // lane
    int q  = tid >> 6;                  // wave
    if (tid < 64) lcodes[tid] = codes[b * T_ + t0 + tid];
    __syncthreads();
    float ax2[16], ad2[16];
#pragma unroll
    for (int p = 0; p < 16; ++p) { ax2[p] = 0.f; ad2[p] = 0.f; }
    for (int c0 = cbase; c0 < cbase + 256; c0 += 64) {
#pragma unroll
        for (int p = 0; p < 16; ++p) {
            int ch = p * 4 + q;
            tile[ch][cx] = student[(size_t)b * (C_ * T_) + (size_t)(c0 + ch) * T_ + t0 + cx];
        }
        __syncthreads();
#pragma unroll
        for (int p = 0; p < 16; ++p) {
            int ty = p * 4 + q;
            float x = tile[cx][ty];
            int n = b * T_ + t0 + ty;
            Abf[(size_t)n * C_ + c0 + cx] = f2bf(x);
            ax2[p] += x * x;
            float cb = codebook[(size_t)lcodes[ty] * C_ + c0 + cx];
            float d = x - cb;
            ad2[p] += d * d;
        }
        __syncthreads();
    }
#pragma unroll
    for (int p = 0; p < 16; ++p) {
        float sx = ax2[p], sd = ad2[p];
#pragma unroll
        for (int m = 1; m < 64; m <<= 1) {
            sx += __shfl_xor(sx, m);
            sd += __shfl_xor(sd, m);
        }
        if (cx == 0) {
            int n = b * T_ + t0 + p * 4 + q;
            atomicAdd(&xnorm[n], sx);
            atomicAdd(&dtg2[n], sd);
        }
    }
}

// ---------------- Kernel 1b: codebook -> bf16 + row norms + init of all reduce buffers -----------
__global__ __launch_bounds__(256) void k1_cb(
    const float* __restrict__ codebook,
    unsigned short* __restrict__ CBbf,
    float* __restrict__ cbnorm,
    float* __restrict__ s_sum,
    unsigned long long* __restrict__ minpack,
    float* __restrict__ xnorm, float* __restrict__ dtg2,
    float* __restrict__ accum)
{
    int tid = threadIdx.x;
    int gidx = blockIdx.x * 256 + tid;
    if (gidx < N_TOK) {
        s_sum[gidx] = 0.f; minpack[gidx] = ~0ull;
        xnorm[gidx] = 0.f; dtg2[gidx] = 0.f;
    }
    if (gidx < 8) accum[gidx] = 0.f;
    int lane = tid & 63;
    int w = tid >> 6;
    int row = blockIdx.x * 4 + w;
    const float* src = codebook + (size_t)row * C_ + lane * 8;
    float4 v0 = *(const float4*)(src);
    float4 v1 = *(const float4*)(src + 4);
    float s = v0.x*v0.x + v0.y*v0.y + v0.z*v0.z + v0.w*v0.w
            + v1.x*v1.x + v1.y*v1.y + v1.z*v1.z + v1.w*v1.w;
    uint4 pk;
    pk.x = (unsigned)f2bf(v0.x) | ((unsigned)f2bf(v0.y) << 16);
    pk.y = (unsigned)f2bf(v0.z) | ((unsigned)f2bf(v0.w) << 16);
    pk.z = (unsigned)f2bf(v1.x) | ((unsigned)f2bf(v1.y) << 16);
    pk.w = (unsigned)f2bf(v1.z) | ((unsigned)f2bf(v1.w) << 16);
    *(uint4*)(CBbf + (size_t)row * C_ + lane * 8) = pk;
#pragma unroll
    for (int m = 1; m < 64; m <<= 1) s += __shfl_xor(s, m);
    if (lane == 0) cbnorm[row] = s;
}

// ---------------- Kernel 2: 256x256, BK=32, 4-slot ring, phase-interleaved, counted vmcnt --------
// grid = 1024 (64 rb x 16 cb, XCD-swizzled); block = 512 (8 waves = 2x4, wave owns 128x64)
// Ring: tiles t..t+2 in LDS; per tile 2 phases, each {ds_read quadrant | 2 stage insts ->
// barrier -> setprio+16 MFMA}. vmcnt(8) BEFORE tile-entry barrier (all waves' stages visible).
// Stage of t+3 hits slot (t-1)&3, two barriers after its last reader (m201 invariant).
__global__ __launch_bounds__(512, 2) void k2_main(
    const unsigned short* __restrict__ Abf,
    const unsigned short* __restrict__ CBbf,
    const float* __restrict__ xnorm,
    const float* __restrict__ dtg2,
    const float* __restrict__ cbnorm,
    float* __restrict__ s_sum,
    unsigned long long* __restrict__ minpack)
{
    __shared__ __align__(16) unsigned short aL[4][256 * 32];   // 4 x 16KB
    __shared__ __align__(16) unsigned short bL[4][256 * 32];   // 4 x 16KB
    int tid = threadIdx.x;
    int lane = tid & 63;
    int w = tid >> 6;                   // 0..7
    int wr = w >> 2, wc = w & 3;        // 2 x 4 wave grid
    int l15 = lane & 15, hi = lane >> 4;

    // XCD-aware swizzle: 1024 % 8 == 0 -> contiguous 128-WG chunk per XCD
    int orig = blockIdx.x;
    int swz = (orig & 7) * 128 + (orig >> 3);
    int rb = swz >> 4, cb = swz & 15;
    int row0 = rb * 256, col0 = cb * 256;

    // Staging: per tile: A = 2 insts/thread, B = 2 insts/thread (16KB each slot-half).
    // inst i covers LDS bytes [(i*512+tid)*16): row = i*128 + (tid>>2), 16B-chunk c = tid&3.
    // T2 swizzle (rule 21, both-sides): LDS chunk c of row r holds global chunk c^(r&3).
    int srow = tid >> 2;
    int sc = (((tid & 3) ^ (srow & 3)) * 8);
    const unsigned short* gA = Abf  + (size_t)(row0 + srow) * C_ + sc;
    const unsigned short* gB = CBbf + (size_t)(col0 + srow) * C_ + sc;

    f32x4 acc[8][4];
#pragma unroll
    for (int rt = 0; rt < 8; ++rt)
#pragma unroll
        for (int ct = 0; ct < 4; ++ct)
            acc[rt][ct] = (f32x4){0.f, 0.f, 0.f, 0.f};

#define STAGE_A(bi, t) do {                                                   \
        stage16(gA + (t) * 32,                   &aL[bi][tid * 8]);           \
        stage16(gA + 128 * (size_t)C_ + (t) * 32, &aL[bi][4096 + tid * 8]);   \
    } while (0)
#define STAGE_B(bi, t) do {                                                   \
        stage16(gB + (t) * 32,                   &bL[bi][tid * 8]);           \
        stage16(gB + 128 * (size_t)C_ + (t) * 32, &bL[bi][4096 + tid * 8]);   \
    } while (0)

    // prologue: tiles 0,1,2 in flight (12 vmem insts/thread)
    STAGE_A(0, 0); STAGE_B(0, 0);
    STAGE_A(1, 1); STAGE_B(1, 1);
    STAGE_A(2, 2); STAGE_B(2, 2);

    int rsw = (hi ^ (l15 & 3)) * 8;     // read-side swizzle (row&3 == l15&3 for all frags)

#pragma unroll
    for (int t = 0; t < 16; ++t) {
        // wait MY stages for tile t landed, THEN barrier -> everyone's tile t visible
        if (t <= 13)      asm volatile("s_waitcnt vmcnt(8)" ::: "memory");
        else if (t == 14) asm volatile("s_waitcnt vmcnt(4)" ::: "memory");
        else              asm volatile("s_waitcnt vmcnt(0)" ::: "memory");
        __builtin_amdgcn_s_barrier();
        const int bi = t & 3;
        const unsigned short* aS = &aL[bi][0];
        const unsigned short* bS = &bL[bi][0];
        short8 af[8], bfr[4];
        // ---- phase 0: read quadrant (A rt0-3 + all B) | stage A(t+3) ----
#pragma unroll
        for (int rt = 0; rt < 4; ++rt)
            af[rt] = *(const short8*)(aS + (wr * 128 + rt * 16 + l15) * 32 + rsw);
#pragma unroll
        for (int ct = 0; ct < 4; ++ct)
            bfr[ct] = *(const short8*)(bS + (wc * 64 + ct * 16 + l15) * 32 + rsw);
        if (t <= 12) STAGE_A((t + 3) & 3, t + 3);
        __builtin_amdgcn_s_barrier();
        __builtin_amdgcn_s_setprio(1);
#pragma unroll
        for (int rt = 0; rt < 4; ++rt)
#pragma unroll
            for (int ct = 0; ct < 4; ++ct)
                acc[rt][ct] = __builtin_amdgcn_mfma_f32_16x16x32_bf16(af[rt], bfr[ct], acc[rt][ct], 0, 0, 0);
        __builtin_amdgcn_s_setprio(0);
        // ---- phase 1: read A rt4-7 | stage B(t+3) ----
#pragma unroll
        for (int rt = 4; rt < 8; ++rt)
            af[rt] = *(const short8*)(aS + (wr * 128 + rt * 16 + l15) * 32 + rsw);
        if (t <= 12) STAGE_B((t + 3) & 3, t + 3);
        __builtin_amdgcn_s_barrier();
        __builtin_amdgcn_s_setprio(1);
#pragma unroll
        for (int rt = 4; rt < 8; ++rt)
#pragma unroll
            for (int ct = 0; ct < 4; ++ct)
                acc[rt][ct] = __builtin_amdgcn_mfma_f32_16x16x32_bf16(af[rt], bfr[ct], acc[rt][ct], 0, 0, 0);
        __builtin_amdgcn_s_setprio(0);
    }
#undef STAGE_A
#undef STAGE_B

    // ---------------- epilogue: dot -> distance -> exp-sum + argmin ----------------
    __syncthreads();                               // full drain; reuse LDS for reduction
    float* red_s = (float*)aL;                     // [256][4] partial sums
    unsigned long long* red_m = (unsigned long long*)bL; // [256][4] packed argmin
    float cbn[4];
#pragma unroll
    for (int ct = 0; ct < 4; ++ct)
        cbn[ct] = cbnorm[col0 + wc * 64 + ct * 16 + l15];
#pragma unroll
    for (int rt = 0; rt < 8; ++rt) {
#pragma unroll
        for (int r = 0; r < 4; ++r) {
            int lrow = wr * 128 + rt * 16 + hi * 4 + r;  // 0..255 within tile
            int row = row0 + lrow;
            float xn = xnorm[row];
            float dt = sqrtf(dtg2[row]);
            float sv = 0.f, dm = 3.4e38f;
            unsigned ix = 0u;
#pragma unroll
            for (int ct = 0; ct < 4; ++ct) {
                float dot = acc[rt][ct][r];
                float d2 = fmaxf(xn + cbn[ct] - 2.f * dot, 0.f);
                float d = sqrtf(d2);
                sv += __expf(fminf(dt - d, 80.f));
                unsigned col = (unsigned)(col0 + wc * 64 + ct * 16 + l15);
                if (d < dm) { dm = d; ix = col; }
            }
#pragma unroll
            for (int m = 1; m < 16; m <<= 1) {
                sv += __shfl_xor(sv, m);
                float od = __shfl_xor(dm, m);
                unsigned oi = __shfl_xor(ix, m);
                if (od < dm || (od == dm && oi < ix)) { dm = od; ix = oi; }
            }
            if (l15 == 0) {
                red_s[lrow * 4 + wc] = sv;
                red_m[lrow * 4 + wc] = ((unsigned long long)__float_as_uint(dm) << 32)
                                     | (unsigned long long)ix;
            }
        }
    }
    __syncthreads();
    if (tid < 256) {
        float sv = red_s[tid * 4 + 0] + red_s[tid * 4 + 1]
                 + red_s[tid * 4 + 2] + red_s[tid * 4 + 3];
        unsigned long long pk = red_m[tid * 4 + 0];
        unsigned long long p1 = red_m[tid * 4 + 1]; if (p1 < pk) pk = p1;
        unsigned long long p2 = red_m[tid * 4 + 2]; if (p2 < pk) pk = p2;
        unsigned long long p3 = red_m[tid * 4 + 3]; if (p3 < pk) pk = p3;
        atomicAdd(&s_sum[row0 + tid], sv);
        atomicMin(&minpack[row0 + tid], pk);
    }
}

// ---------------- Kernel 3a: per-token CE/accuracy/emb-loss/target-dist reduce ----------------
__global__ __launch_bounds__(256) void k3a(
    const float* __restrict__ s_sum,
    const unsigned long long* __restrict__ minpack,
    const int* __restrict__ codes,
    const float* __restrict__ dtg2,
    float* __restrict__ accum)
{
    __shared__ float w0[4], w1[4], w2[4], w3[4];
    int tid = threadIdx.x;
    int n = blockIdx.x * 256 + tid;
    float ce = logf(s_sum[n]);
    unsigned pred = (unsigned)(minpack[n] & 0xFFFFFFFFull);
    float ok = (pred == (unsigned)codes[n]) ? 1.f : 0.f;
    float sq = dtg2[n];
    float td = sqrtf(sq);
#pragma unroll
    for (int m = 1; m < 64; m <<= 1) {
        ce += __shfl_xor(ce, m);
        ok += __shfl_xor(ok, m);
        sq += __shfl_xor(sq, m);
        td += __shfl_xor(td, m);
    }
    int lane = tid & 63, w = tid >> 6;
    if (lane == 0) { w0[w] = ce; w1[w] = ok; w2[w] = sq; w3[w] = td; }
    __syncthreads();
    if (tid == 0) {
        atomicAdd(&accum[0], w0[0] + w0[1] + w0[2] + w0[3]);
        atomicAdd(&accum[1], w1[0] + w1[1] + w1[2] + w1[3]);
        atomicAdd(&accum[2], w2[0] + w2[1] + w2[2] + w2[3]);
        atomicAdd(&accum[3], w3[0] + w3[1] + w3[2] + w3[3]);
    }
}

// ---------------- Kernel 3b: finalize 5 outputs ----------------
__global__ void k3b(const float* __restrict__ accum, float* __restrict__ out)
{
    if (threadIdx.x == 0 && blockIdx.x == 0) {
        float ce   = accum[0] / (float)N_TOK;
        float accy = accum[1] / (float)N_TOK;
        float emb  = accum[2] / ((float)N_TOK * (float)C_);
        float td   = accum[3] / (float)N_TOK;
        out[0] = emb + ce;   // total_loss (EMB_W=CE_W=1)
        out[1] = emb;        // emb_to_codebook_loss
        out[2] = ce;         // ce_loss
        out[3] = accy;       // token_accuracy
        out[4] = td;         // emb_to_target_dist
    }
}

extern "C" void kernel_launch(void* const* d_in, const int* in_sizes, int n_in,
                              void* d_out, int out_size, void* d_ws, size_t ws_size,
                              hipStream_t stream)
{
    const float* student  = (const float*)d_in[0];
    const int*   codes    = (const int*)d_in[1];
    const float* codebook = (const float*)d_in[2];
    // d_in[3] distance_matrix is unused by the reference.
    float* out = (float*)d_out;

    char* ws = (char*)d_ws;
    unsigned short* Abf   = (unsigned short*)(ws);                 // 16 MiB
    unsigned short* CBbf  = (unsigned short*)(ws + 16777216);      // 4 MiB
    float* xnorm          = (float*)(ws + 20971520);               // 64 KiB
    float* dtg2           = (float*)(ws + 21037056);               // 64 KiB
    float* cbnorm         = (float*)(ws + 21102592);               // 16 KiB
    float* s_sum          = (float*)(ws + 21118976);               // 64 KiB
    unsigned long long* minpack = (unsigned long long*)(ws + 21184512); // 128 KiB
    float* accum          = (float*)(ws + 21315584);               // 64 B

    // k1_cb zero-inits s_sum/minpack/xnorm/dtg2/accum (stream-ordered before k1_prep's atomics)
    hipLaunchKernelGGL(k1_cb, dim3(1024), dim3(256), 0, stream,
                       codebook, CBbf, cbnorm, s_sum, minpack, xnorm, dtg2, accum);
    hipLaunchKernelGGL(k1_prep, dim3(512), dim3(256), 0, stream,
                       student, codes, codebook, Abf, xnorm, dtg2);
    hipLaunchKernelGGL(k2_main, dim3(1024), dim3(512), 0, stream,
                       Abf, CBbf, xnorm, dtg2, cbnorm, s_sum, minpack);
    hipLaunchKernelGGL(k3a, dim3(64), dim3(256), 0, stream,
                       s_sum, minpack, codes, dtg2, accum);
    hipLaunchKernelGGL(k3b, dim3(1), dim3(64), 0, stream, accum, out);
}

// Round 7
// 214.514 us; speedup vs baseline: 1.5225x; 1.0153x over previous
//
#include <hip/hip_runtime.h>
#include <hip/hip_fp8.h>

#define C_ 512
#define T_ 2048
#define N_TOK 16384
#define K_CB 4096

typedef __attribute__((ext_vector_type(4))) float f32x4;

static __device__ __forceinline__ unsigned char f2fp8(float f) {
    __hip_fp8_e4m3 v(f);                 // OCP e4m3, RNE + saturate (gfx950 HW path)
    return (unsigned char)v.__x;
}

// ---------------- Kernel 1: transpose student (B,C,T)->(N,C) fp8 + per-token partial stats ------
// grid = 512: 256 token-tiles x 2 C-halves. Partials via atomicAdd (zero-init by k1_cb).
__global__ __launch_bounds__(256) void k1_prep(
    const float* __restrict__ student,   // (B,C,T) fp32
    const int* __restrict__ codes,       // (B,T) int32
    const float* __restrict__ codebook,  // (K,C) fp32
    unsigned char* __restrict__ A8,      // (N,C) fp8 out
    float* __restrict__ xnorm, float* __restrict__ dtg2)
{
    __shared__ float tile[64][65];
    __shared__ int lcodes[64];
    int tid = threadIdx.x;
    int tnum  = blockIdx.x >> 1;
    int chalf = blockIdx.x & 1;
    int b  = tnum >> 5;
    int t0 = (tnum & 31) << 6;
    int cbase = chalf << 8;             // 0 or 256
    int cx = tid & 63;                  // lane
    int q  = tid >> 6;                  // wave
    if (tid < 64) lcodes[tid] = codes[b * T_ + t0 + tid];
    __syncthreads();
    float ax2[16], ad2[16];
#pragma unroll
    for (int p = 0; p < 16; ++p) { ax2[p] = 0.f; ad2[p] = 0.f; }
    for (int c0 = cbase; c0 < cbase + 256; c0 += 64) {
#pragma unroll
        for (int p = 0; p < 16; ++p) {
            int ch = p * 4 + q;
            tile[ch][cx] = student[(size_t)b * (C_ * T_) + (size_t)(c0 + ch) * T_ + t0 + cx];
        }
        __syncthreads();
#pragma unroll
        for (int p = 0; p < 16; ++p) {
            int ty = p * 4 + q;
            float x = tile[cx][ty];
            int n = b * T_ + t0 + ty;
            A8[(size_t)n * C_ + c0 + cx] = f2fp8(x);
            ax2[p] += x * x;
            float cb = codebook[(size_t)lcodes[ty] * C_ + c0 + cx];
            float d = x - cb;
            ad2[p] += d * d;
        }
        __syncthreads();
    }
#pragma unroll
    for (int p = 0; p < 16; ++p) {
        float sx = ax2[p], sd = ad2[p];
#pragma unroll
        for (int m = 1; m < 64; m <<= 1) {
            sx += __shfl_xor(sx, m);
            sd += __shfl_xor(sd, m);
        }
        if (cx == 0) {
            int n = b * T_ + t0 + p * 4 + q;
            atomicAdd(&xnorm[n], sx);
            atomicAdd(&dtg2[n], sd);
        }
    }
}

// ---------------- Kernel 1b: codebook -> fp8 + row norms + init of all reduce buffers -----------
__global__ __launch_bounds__(256) void k1_cb(
    const float* __restrict__ codebook,
    unsigned char* __restrict__ B8,
    float* __restrict__ cbnorm,
    float* __restrict__ s_sum,
    unsigned long long* __restrict__ minpack,
    float* __restrict__ xnorm, float* __restrict__ dtg2,
    float* __restrict__ accum)
{
    int tid = threadIdx.x;
    int gidx = blockIdx.x * 256 + tid;
    if (gidx < N_TOK) {
        s_sum[gidx] = 0.f; minpack[gidx] = ~0ull;
        xnorm[gidx] = 0.f; dtg2[gidx] = 0.f;
    }
    if (gidx < 8) accum[gidx] = 0.f;
    int lane = tid & 63;
    int w = tid >> 6;
    int row = blockIdx.x * 4 + w;
    const float* src = codebook + (size_t)row * C_ + lane * 8;
    float4 v0 = *(const float4*)(src);
    float4 v1 = *(const float4*)(src + 4);
    float s = v0.x*v0.x + v0.y*v0.y + v0.z*v0.z + v0.w*v0.w
            + v1.x*v1.x + v1.y*v1.y + v1.z*v1.z + v1.w*v1.w;
    unsigned lo = (unsigned)f2fp8(v0.x) | ((unsigned)f2fp8(v0.y) << 8)
                | ((unsigned)f2fp8(v0.z) << 16) | ((unsigned)f2fp8(v0.w) << 24);
    unsigned hi = (unsigned)f2fp8(v1.x) | ((unsigned)f2fp8(v1.y) << 8)
                | ((unsigned)f2fp8(v1.z) << 16) | ((unsigned)f2fp8(v1.w) << 24);
    *(uint2*)(B8 + (size_t)row * C_ + lane * 8) = make_uint2(lo, hi);
#pragma unroll
    for (int m = 1; m < 64; m <<= 1) s += __shfl_xor(s, m);
    if (lane == 0) cbnorm[row] = s;
}

// granule reorder for source-side swizzle: out[i] = g[i^x3], g = (v0.xy, v0.zw, v1.xy, v1.zw)
static __device__ __forceinline__ void wr32(unsigned char* dst, uint4 v0, uint4 v1, int x3) {
    uint4 w0, w1;
    if (x3 == 0)      { w0 = v0; w1 = v1; }
    else if (x3 == 1) { w0 = make_uint4(v0.z,v0.w,v0.x,v0.y); w1 = make_uint4(v1.z,v1.w,v1.x,v1.y); }
    else if (x3 == 2) { w0 = v1; w1 = v0; }
    else              { w0 = make_uint4(v1.z,v1.w,v1.x,v1.y); w1 = make_uint4(v0.z,v0.w,v0.x,v0.y); }
    *(uint4*)dst = w0; *(uint4*)(dst + 16) = w1;
}

// ---------------- Kernel 2: fp8 MFMA GEMM, reg-staged prefetch-2, swizzled LDS, 3 WG/CU ---------
// grid = 1024 (128 rb x 8 cs, XCD-chunked: per XCD 16 rb x 8 cs -> A 1MB + B 2MB fits L2)
// block = 256 (4 waves = 2x2 of 64x64). WG output = 128 rows x 512 cols (4 cc-chunks of 128).
// K=512, BK=64 fp8: 8 K-steps per cc, 32 steps total, fully unrolled; 2 barriers/step.
// LDS tile swizzle: slot s (8B) of row r holds global granule s ^ ((r>>1)&7) -> ds_read 2-way max.
__global__ __launch_bounds__(256) void k2_main(
    const unsigned char* __restrict__ A8,
    const unsigned char* __restrict__ B8,
    const float* __restrict__ xnorm,
    const float* __restrict__ dtg2,
    const float* __restrict__ cbnorm,
    float* __restrict__ s_sum,
    unsigned long long* __restrict__ minpack)
{
    __shared__ __align__(16) unsigned char aS[128 * 64];     // 8 KB
    __shared__ __align__(16) unsigned char bS[128 * 64];     // 8 KB
    __shared__ float red_s[256];                             // [lrow][wc]
    __shared__ unsigned long long red_m[256];
    int tid = threadIdx.x;
    int lane = tid & 63;
    int w = tid >> 6;
    int wr = w >> 1, wc = w & 1;
    int l15 = lane & 15, hi = lane >> 4;
    int sl = l15 >> 1;                   // read-side row swizzle

    int orig = blockIdx.x;
    int swz = (orig & 7) * 128 + (orig >> 3);
    int rb = swz >> 3, cs = swz & 7;
    int row0 = rb * 128, colbase = cs * 512;

    // staging: thread t owns row r = t>>1, LDS slots s0..s0+3 (32B); source granule base
    // gb = s0 ^ (xr&4), within-load permutation by x3 = xr&3 (wr32).
    int r = tid >> 1;
    int xr = (r >> 1) & 7;
    int x3 = xr & 3;
    int s0 = (tid & 1) * 4;
    int gb = s0 ^ (xr & 4);
    const unsigned char* gArow = A8 + (size_t)(row0 + r) * C_ + gb * 8;
    const unsigned char* gBrow = B8 + (size_t)(colbase + r) * C_ + gb * 8;
    unsigned char* aW = aS + r * 64 + s0 * 8;
    unsigned char* bW = bS + r * 64 + s0 * 8;

    if (tid < 256) { red_s[tid] = 0.f; red_m[tid] = ~0ull; }

    f32x4 acc[4][4];
#pragma unroll
    for (int rt = 0; rt < 4; ++rt)
#pragma unroll
        for (int ct = 0; ct < 4; ++ct)
            acc[rt][ct] = (f32x4){0.f, 0.f, 0.f, 0.f};

#define LOADSET(A0, A1, B0, B1, s) do {                                        \
        const unsigned char* ap_ = gArow + ((s) & 7) * 64;                     \
        const unsigned char* bp_ = gBrow + (size_t)((s) >> 3) * (128 * C_) + ((s) & 7) * 64; \
        A0 = *(const uint4*)(ap_); A1 = *(const uint4*)(ap_ + 16);             \
        B0 = *(const uint4*)(bp_); B1 = *(const uint4*)(bp_ + 16);             \
    } while (0)

    uint4 pa0, pa1, pb0, pb1, qa0, qa1, qb0, qb1;
    LOADSET(pa0, pa1, pb0, pb1, 0);
    LOADSET(qa0, qa1, qb0, qb1, 1);

#pragma unroll
    for (int s = 0; s < 32; ++s) {
        __syncthreads();                 // prior step's ds_reads complete
        if ((s & 1) == 0) { wr32(aW, pa0, pa1, x3); wr32(bW, pb0, pb1, x3); }
        else              { wr32(aW, qa0, qa1, x3); wr32(bW, qb0, qb1, x3); }
        __syncthreads();                 // tile s visible
        if (s < 30) {                    // issue loads for s+2 into the freed set (~2-step slack)
            if ((s & 1) == 0) LOADSET(pa0, pa1, pb0, pb1, s + 2);
            else              LOADSET(qa0, qa1, qb0, qb1, s + 2);
        }
#pragma unroll
        for (int kk = 0; kk < 2; ++kk) {
            long afr[4], bfr[4];
#pragma unroll
            for (int rt = 0; rt < 4; ++rt)
                afr[rt] = *(const long*)(aS + (wr * 64 + rt * 16 + l15) * 64 + (((kk * 4 + hi) ^ sl)) * 8);
#pragma unroll
            for (int ct = 0; ct < 4; ++ct)
                bfr[ct] = *(const long*)(bS + (wc * 64 + ct * 16 + l15) * 64 + (((kk * 4 + hi) ^ sl)) * 8);
            __builtin_amdgcn_s_setprio(1);
#pragma unroll
            for (int rt = 0; rt < 4; ++rt)
#pragma unroll
                for (int ct = 0; ct < 4; ++ct)
                    acc[rt][ct] = __builtin_amdgcn_mfma_f32_16x16x32_fp8_fp8(afr[rt], bfr[ct], acc[rt][ct], 0, 0, 0);
            __builtin_amdgcn_s_setprio(0);
        }
        if ((s & 7) == 7) {
            // ---- per-cc epilogue: dot -> distance -> exp-sum + argmin, accumulate in LDS ----
            int col0 = colbase + (s >> 3) * 128;
            float cbn[4];
#pragma unroll
            for (int ct = 0; ct < 4; ++ct)
                cbn[ct] = cbnorm[col0 + wc * 64 + ct * 16 + l15];
#pragma unroll
            for (int rt = 0; rt < 4; ++rt) {
#pragma unroll
                for (int rr = 0; rr < 4; ++rr) {
                    int lrow = wr * 64 + rt * 16 + hi * 4 + rr;
                    float xn = xnorm[row0 + lrow];
                    float dt = sqrtf(dtg2[row0 + lrow]);
                    float sv = 0.f, dm = 3.4e38f;
                    unsigned ix = 0u;
#pragma unroll
                    for (int ct = 0; ct < 4; ++ct) {
                        float dot = acc[rt][ct][rr];
                        float d2 = fmaxf(xn + cbn[ct] - 2.f * dot, 0.f);
                        float d = sqrtf(d2);
                        sv += __expf(fminf(dt - d, 80.f));
                        unsigned col = (unsigned)(col0 + wc * 64 + ct * 16 + l15);
                        if (d < dm) { dm = d; ix = col; }
                    }
#pragma unroll
                    for (int m = 1; m < 16; m <<= 1) {
                        sv += __shfl_xor(sv, m);
                        float od = __shfl_xor(dm, m);
                        unsigned oi = __shfl_xor(ix, m);
                        if (od < dm || (od == dm && oi < ix)) { dm = od; ix = oi; }
                    }
                    if (l15 == 0) {
                        int ri = lrow * 2 + wc;      // unique per (wave, hi, rt, rr): no race
                        red_s[ri] += sv;
                        unsigned long long pk = ((unsigned long long)__float_as_uint(dm) << 32)
                                              | (unsigned long long)ix;
                        if (pk < red_m[ri]) red_m[ri] = pk;
                    }
                    acc[rt][0] = (f32x4){0.f,0.f,0.f,0.f}; acc[rt][1] = (f32x4){0.f,0.f,0.f,0.f};
                    acc[rt][2] = (f32x4){0.f,0.f,0.f,0.f}; acc[rt][3] = (f32x4){0.f,0.f,0.f,0.f};
                }
            }
        }
    }
#undef LOADSET

    __syncthreads();
    if (tid < 128) {
        float sv = red_s[tid * 2] + red_s[tid * 2 + 1];
        unsigned long long p0 = red_m[tid * 2], p1 = red_m[tid * 2 + 1];
        unsigned long long pk = p1 < p0 ? p1 : p0;
        atomicAdd(&s_sum[row0 + tid], sv);
        atomicMin(&minpack[row0 + tid], pk);
    }
}

// ---------------- Kernel 3a: per-token CE/accuracy/emb-loss/target-dist reduce ----------------
__global__ __launch_bounds__(256) void k3a(
    const float* __restrict__ s_sum,
    const unsigned long long* __restrict__ minpack,
    const int* __restrict__ codes,
    const float* __restrict__ dtg2,
    float* __restrict__ accum)
{
    __shared__ float w0[4], w1[4], w2[4], w3[4];
    int tid = threadIdx.x;
    int n = blockIdx.x * 256 + tid;
    float ce = logf(s_sum[n]);           // = d_t + lse(-d) = per-token CE
    unsigned pred = (unsigned)(minpack[n] & 0xFFFFFFFFull);
    float ok = (pred == (unsigned)codes[n]) ? 1.f : 0.f;
    float sq = dtg2[n];
    float td = sqrtf(sq);
#pragma unroll
    for (int m = 1; m < 64; m <<= 1) {
        ce += __shfl_xor(ce, m);
        ok += __shfl_xor(ok, m);
        sq += __shfl_xor(sq, m);
        td += __shfl_xor(td, m);
    }
    int lane = tid & 63, w = tid >> 6;
    if (lane == 0) { w0[w] = ce; w1[w] = ok; w2[w] = sq; w3[w] = td; }
    __syncthreads();
    if (tid == 0) {
        atomicAdd(&accum[0], w0[0] + w0[1] + w0[2] + w0[3]);
        atomicAdd(&accum[1], w1[0] + w1[1] + w1[2] + w1[3]);
        atomicAdd(&accum[2], w2[0] + w2[1] + w2[2] + w2[3]);
        atomicAdd(&accum[3], w3[0] + w3[1] + w3[2] + w3[3]);
    }
}

// ---------------- Kernel 3b: finalize 5 outputs ----------------
__global__ void k3b(const float* __restrict__ accum, float* __restrict__ out)
{
    if (threadIdx.x == 0 && blockIdx.x == 0) {
        float ce   = accum[0] / (float)N_TOK;
        float accy = accum[1] / (float)N_TOK;
        float emb  = accum[2] / ((float)N_TOK * (float)C_);
        float td   = accum[3] / (float)N_TOK;
        out[0] = emb + ce;   // total_loss (EMB_W=CE_W=1)
        out[1] = emb;        // emb_to_codebook_loss
        out[2] = ce;         // ce_loss
        out[3] = accy;       // token_accuracy
        out[4] = td;         // emb_to_target_dist
    }
}

extern "C" void kernel_launch(void* const* d_in, const int* in_sizes, int n_in,
                              void* d_out, int out_size, void* d_ws, size_t ws_size,
                              hipStream_t stream)
{
    const float* student  = (const float*)d_in[0];
    const int*   codes    = (const int*)d_in[1];
    const float* codebook = (const float*)d_in[2];
    // d_in[3] distance_matrix is unused by the reference.
    float* out = (float*)d_out;

    char* ws = (char*)d_ws;
    unsigned char* A8     = (unsigned char*)(ws);                  // 8 MiB
    unsigned char* B8     = (unsigned char*)(ws + 8388608);        // 2 MiB
    float* xnorm          = (float*)(ws + 10485760);               // 64 KiB
    float* dtg2           = (float*)(ws + 10551296);               // 64 KiB
    float* cbnorm         = (float*)(ws + 10616832);               // 16 KiB
    float* s_sum          = (float*)(ws + 10633216);               // 64 KiB
    unsigned long long* minpack = (unsigned long long*)(ws + 10698752); // 128 KiB
    float* accum          = (float*)(ws + 10829824);               // 64 B

    // k1_cb zero-inits s_sum/minpack/xnorm/dtg2/accum (stream-ordered before k1_prep's atomics)
    hipLaunchKernelGGL(k1_cb, dim3(1024), dim3(256), 0, stream,
                       codebook, B8, cbnorm, s_sum, minpack, xnorm, dtg2, accum);
    hipLaunchKernelGGL(k1_prep, dim3(512), dim3(256), 0, stream,
                       student, codes, codebook, A8, xnorm, dtg2);
    hipLaunchKernelGGL(k2_main, dim3(1024), dim3(256), 0, stream,
                       A8, B8, xnorm, dtg2, cbnorm, s_sum, minpack);
    hipLaunchKernelGGL(k3a, dim3(64), dim3(256), 0, stream,
                       s_sum, minpack, codes, dtg2, accum);
    hipLaunchKernelGGL(k3b, dim3(1), dim3(64), 0, stream, accum, out);
}